// Round 1
// baseline (1691.441 us; speedup 1.0000x reference)
//
#include <hip/hip_runtime.h>

#define N_NODES 100000
#define N_EDGES 1600000
#define NODE_DIM 24
#define HIDDEN 128

// ---------------------------------------------------------------------------
// K1: h[n][j] = b_in[j] + sum_d x[n][d] * W_in[d][j]
// 256 threads = 2 node-lanes of 128. W_in (12 KB) + b_in staged in LDS.
// ---------------------------------------------------------------------------
__global__ __launch_bounds__(256) void node_init_kernel(
    const float* __restrict__ x, const float* __restrict__ W_in,
    const float* __restrict__ b_in, float* __restrict__ h) {
  __shared__ float w_lds[NODE_DIM * HIDDEN];
  __shared__ float b_lds[HIDDEN];
  for (int i = threadIdx.x; i < NODE_DIM * HIDDEN; i += blockDim.x) w_lds[i] = W_in[i];
  if (threadIdx.x < HIDDEN) b_lds[threadIdx.x] = b_in[threadIdx.x];
  __syncthreads();
  const int j = threadIdx.x & 127;
  const int g = threadIdx.x >> 7;
  for (int n = blockIdx.x * 2 + g; n < N_NODES; n += gridDim.x * 2) {
    float acc = b_lds[j];
    const float* xr = x + n * NODE_DIM;
#pragma unroll
    for (int d = 0; d < NODE_DIM; ++d) acc = fmaf(xr[d], w_lds[d * HIDDEN + j], acc);
    h[n * HIDDEN + j] = acc;
  }
}

// ---------------------------------------------------------------------------
// K2: per edge: m = relu(h[src] + (ea0*We0 + ea1*We1 + be)); agg[dst] += m
// 256 threads = 2 edge-lanes of 128. unsafeAtomicAdd -> global_atomic_add_f32.
// ---------------------------------------------------------------------------
__global__ __launch_bounds__(256) void edge_scatter_kernel(
    const int* __restrict__ ei, const float* __restrict__ ea,
    const float* __restrict__ W_e, const float* __restrict__ b_e,
    const float* __restrict__ h, float* __restrict__ agg) {
  const int j = threadIdx.x & 127;
  const int g = threadIdx.x >> 7;
  const float we0 = W_e[j];
  const float we1 = W_e[HIDDEN + j];
  const float be = b_e[j];
  const int* __restrict__ srcs = ei;
  const int* __restrict__ dsts = ei + N_EDGES;
  const float2* __restrict__ ea2 = (const float2*)ea;
  for (int e = blockIdx.x * 2 + g; e < N_EDGES; e += gridDim.x * 2) {
    const int s = srcs[e];
    const int d = dsts[e];
    const float2 a = ea2[e];
    float m = h[s * HIDDEN + j] + fmaf(a.x, we0, fmaf(a.y, we1, be));
    m = m > 0.f ? m : 0.f;
    unsafeAtomicAdd(&agg[d * HIDDEN + j], m);
  }
}

// ---------------------------------------------------------------------------
// K3: z = h + agg; out = [relu]( relu(z@W1+b1) @ W2 + b2 )
// 256 threads (2 halves x 128 lanes), 32 nodes per block. In-place safe:
// each block reads exactly the rows it writes, reads complete before writes.
// ---------------------------------------------------------------------------
template <bool RELU_OUT>
__global__ __launch_bounds__(256) void mlp_kernel(
    const float* __restrict__ hbuf, const float* __restrict__ agg,
    const float* __restrict__ W1, const float* __restrict__ b1,
    const float* __restrict__ W2, const float* __restrict__ b2,
    float* __restrict__ out) {
  const int NB = 32;        // nodes per block
  const int NT = 16;        // nodes per thread-half
  __shared__ float zs[NB][HIDDEN];
  __shared__ float ts[NB][HIDDEN];
  const int j = threadIdx.x & 127;
  const int g = threadIdx.x >> 7;  // which half of the node batch
  const int n0 = blockIdx.x * NB;

#pragma unroll
  for (int n = 0; n < NT; ++n) {
    const int nn = g * NT + n;
    zs[nn][j] = hbuf[(n0 + nn) * HIDDEN + j] + agg[(n0 + nn) * HIDDEN + j];
  }
  __syncthreads();

  float acc[NT];
  const float b1j = b1[j];
#pragma unroll
  for (int n = 0; n < NT; ++n) acc[n] = b1j;
  for (int k = 0; k < HIDDEN; k += 4) {
    const float w0 = W1[(k + 0) * HIDDEN + j];
    const float w1 = W1[(k + 1) * HIDDEN + j];
    const float w2 = W1[(k + 2) * HIDDEN + j];
    const float w3 = W1[(k + 3) * HIDDEN + j];
#pragma unroll
    for (int n = 0; n < NT; ++n) {
      const float4 z = *reinterpret_cast<const float4*>(&zs[g * NT + n][k]);
      acc[n] = fmaf(z.x, w0, acc[n]);
      acc[n] = fmaf(z.y, w1, acc[n]);
      acc[n] = fmaf(z.z, w2, acc[n]);
      acc[n] = fmaf(z.w, w3, acc[n]);
    }
  }
#pragma unroll
  for (int n = 0; n < NT; ++n) ts[g * NT + n][j] = acc[n] > 0.f ? acc[n] : 0.f;
  __syncthreads();

  const float b2j = b2[j];
#pragma unroll
  for (int n = 0; n < NT; ++n) acc[n] = b2j;
  for (int k = 0; k < HIDDEN; k += 4) {
    const float w0 = W2[(k + 0) * HIDDEN + j];
    const float w1 = W2[(k + 1) * HIDDEN + j];
    const float w2 = W2[(k + 2) * HIDDEN + j];
    const float w3 = W2[(k + 3) * HIDDEN + j];
#pragma unroll
    for (int n = 0; n < NT; ++n) {
      const float4 z = *reinterpret_cast<const float4*>(&ts[g * NT + n][k]);
      acc[n] = fmaf(z.x, w0, acc[n]);
      acc[n] = fmaf(z.y, w1, acc[n]);
      acc[n] = fmaf(z.z, w2, acc[n]);
      acc[n] = fmaf(z.w, w3, acc[n]);
    }
  }
#pragma unroll
  for (int n = 0; n < NT; ++n) {
    float v = acc[n];
    if (RELU_OUT) v = v > 0.f ? v : 0.f;
    out[(n0 + g * NT + n) * HIDDEN + j] = v;
  }
}

extern "C" void kernel_launch(void* const* d_in, const int* in_sizes, int n_in,
                              void* d_out, int out_size, void* d_ws, size_t ws_size,
                              hipStream_t stream) {
  const float* x    = (const float*)d_in[0];
  const int*   ei   = (const int*)d_in[1];
  const float* ea   = (const float*)d_in[2];
  const float* W_in = (const float*)d_in[3];
  const float* b_in = (const float*)d_in[4];
  const float* W_e  = (const float*)d_in[5];
  const float* b_e  = (const float*)d_in[6];
  const float* W1   = (const float*)d_in[7];
  const float* b1   = (const float*)d_in[8];
  const float* W2   = (const float*)d_in[9];
  const float* b2   = (const float*)d_in[10];

  float* h   = (float*)d_out;  // node feature buffer, rewritten in place each stage
  float* agg = (float*)d_ws;   // 100000*128*4 = 51.2 MB scratch
  const size_t agg_bytes = (size_t)N_NODES * HIDDEN * sizeof(float);

  // h0 = x @ W_in + b_in
  node_init_kernel<<<2048, 256, 0, stream>>>(x, W_in, b_in, h);

  // ---- conv1 ----
  hipMemsetAsync(agg, 0, agg_bytes, stream);
  edge_scatter_kernel<<<4096, 256, 0, stream>>>(ei, ea, W_e, b_e, h, agg);
  mlp_kernel<true><<<N_NODES / 32, 256, 0, stream>>>(h, agg, W1, b1, W2, b2, h);

  // ---- conv2 ----
  hipMemsetAsync(agg, 0, agg_bytes, stream);
  edge_scatter_kernel<<<4096, 256, 0, stream>>>(ei, ea, W_e, b_e, h, agg);
  mlp_kernel<false><<<N_NODES / 32, 256, 0, stream>>>(h, agg, W1, b1, W2, b2, h);
}

// Round 2
// 873.349 us; speedup vs baseline: 1.9367x; 1.9367x over previous
//
#include <hip/hip_runtime.h>

#define N_NODES 100000
#define N_EDGES 1600000
#define NODE_DIM 24
#define HIDDEN 128
#define NCHUNK 391  // ceil(N_NODES/256)

// ---------------------------------------------------------------------------
// K1: h[n][j] = b_in[j] + sum_d x[n][d] * W_in[d][j]
// ---------------------------------------------------------------------------
__global__ __launch_bounds__(256) void node_init_kernel(
    const float* __restrict__ x, const float* __restrict__ W_in,
    const float* __restrict__ b_in, float* __restrict__ h) {
  __shared__ float w_lds[NODE_DIM * HIDDEN];
  __shared__ float b_lds[HIDDEN];
  for (int i = threadIdx.x; i < NODE_DIM * HIDDEN; i += blockDim.x) w_lds[i] = W_in[i];
  if (threadIdx.x < HIDDEN) b_lds[threadIdx.x] = b_in[threadIdx.x];
  __syncthreads();
  const int j = threadIdx.x & 127;
  const int g = threadIdx.x >> 7;
  for (int n = blockIdx.x * 2 + g; n < N_NODES; n += gridDim.x * 2) {
    float acc = b_lds[j];
    const float* xr = x + n * NODE_DIM;
#pragma unroll
    for (int d = 0; d < NODE_DIM; ++d) acc = fmaf(xr[d], w_lds[d * HIDDEN + j], acc);
    h[n * HIDDEN + j] = acc;
  }
}

// ---------------------------------------------------------------------------
// CSR build: histogram -> 3-step exclusive scan -> permute fill
// ---------------------------------------------------------------------------
__global__ __launch_bounds__(256) void k_hist(const int* __restrict__ dsts,
                                              int* __restrict__ deg) {
  int e = blockIdx.x * 256 + threadIdx.x;
  if (e < N_EDGES) atomicAdd(&deg[dsts[e]], 1);
}

__global__ __launch_bounds__(256) void k_chunk_sum(const int* __restrict__ deg,
                                                   int* __restrict__ bsum) {
  __shared__ int s[256];
  int n = blockIdx.x * 256 + threadIdx.x;
  s[threadIdx.x] = (n < N_NODES) ? deg[n] : 0;
  __syncthreads();
  for (int d = 128; d > 0; d >>= 1) {
    if (threadIdx.x < d) s[threadIdx.x] += s[threadIdx.x + d];
    __syncthreads();
  }
  if (threadIdx.x == 0) bsum[blockIdx.x] = s[0];
}

__global__ __launch_bounds__(512) void k_scan_bsum(const int* __restrict__ bsum,
                                                   int* __restrict__ boff) {
  __shared__ int s[512];
  const int t = threadIdx.x;
  int v = (t < NCHUNK) ? bsum[t] : 0;
  s[t] = v;
  __syncthreads();
  for (int d = 1; d < 512; d <<= 1) {
    int x = (t >= d) ? s[t - d] : 0;
    __syncthreads();
    s[t] += x;
    __syncthreads();
  }
  if (t < NCHUNK) boff[t] = s[t] - v;  // exclusive
}

__global__ __launch_bounds__(256) void k_off(const int* __restrict__ deg,
                                             const int* __restrict__ boff,
                                             int* __restrict__ off,
                                             int* __restrict__ cursor) {
  __shared__ int s[256];
  const int t = threadIdx.x;
  int n = blockIdx.x * 256 + t;
  int v = (n < N_NODES) ? deg[n] : 0;
  s[t] = v;
  __syncthreads();
  for (int d = 1; d < 256; d <<= 1) {
    int x = (t >= d) ? s[t - d] : 0;
    __syncthreads();
    s[t] += x;
    __syncthreads();
  }
  if (n < N_NODES) {
    int o = boff[blockIdx.x] + s[t] - v;
    off[n] = o;
    cursor[n] = o;
  }
}

__global__ __launch_bounds__(256) void k_fill(const int* __restrict__ srcs,
                                              const int* __restrict__ dsts,
                                              const float2* __restrict__ ea2,
                                              int* __restrict__ cursor,
                                              int* __restrict__ psrc,
                                              float2* __restrict__ pea) {
  int e = blockIdx.x * 256 + threadIdx.x;
  if (e < N_EDGES) {
    int pos = atomicAdd(&cursor[dsts[e]], 1);
    psrc[pos] = srcs[e];
    pea[pos] = ea2[e];
  }
}

// ---------------------------------------------------------------------------
// Gather-aggregate: z[n] = h[n] + sum_{e: dst=n} relu(h[src_e] + We*ea_e + be)
// one 128-lane group per node; h row reads are 512B coalesced, L3-resident.
// ---------------------------------------------------------------------------
__global__ __launch_bounds__(256) void gather_z_kernel(
    const int* __restrict__ off, const int* __restrict__ deg,
    const int* __restrict__ psrc, const float2* __restrict__ pea,
    const float* __restrict__ W_e, const float* __restrict__ b_e,
    const float* __restrict__ h, float* __restrict__ z) {
  const int j = threadIdx.x & 127;
  const int g = threadIdx.x >> 7;
  const float we0 = W_e[j], we1 = W_e[HIDDEN + j], be = b_e[j];
  for (int n = blockIdx.x * 2 + g; n < N_NODES; n += gridDim.x * 2) {
    float acc = h[n * HIDDEN + j];
    const int o = off[n];
    const int d = deg[n];
    int t = 0;
    for (; t + 1 < d; t += 2) {
      const int s0 = psrc[o + t];
      const int s1 = psrc[o + t + 1];
      const float2 a0 = pea[o + t];
      const float2 a1 = pea[o + t + 1];
      float m0 = h[s0 * HIDDEN + j] + fmaf(a0.x, we0, fmaf(a0.y, we1, be));
      float m1 = h[s1 * HIDDEN + j] + fmaf(a1.x, we0, fmaf(a1.y, we1, be));
      acc += (m0 > 0.f ? m0 : 0.f) + (m1 > 0.f ? m1 : 0.f);
    }
    if (t < d) {
      const int s0 = psrc[o + t];
      const float2 a0 = pea[o + t];
      float m0 = h[s0 * HIDDEN + j] + fmaf(a0.x, we0, fmaf(a0.y, we1, be));
      acc += m0 > 0.f ? m0 : 0.f;
    }
    z[n * HIDDEN + j] = acc;
  }
}

// ---------------------------------------------------------------------------
// Fallback scatter (old path) if ws too small
// ---------------------------------------------------------------------------
__global__ __launch_bounds__(256) void edge_scatter_kernel(
    const int* __restrict__ ei, const float* __restrict__ ea,
    const float* __restrict__ W_e, const float* __restrict__ b_e,
    const float* __restrict__ h, float* __restrict__ agg) {
  const int j = threadIdx.x & 127;
  const int g = threadIdx.x >> 7;
  const float we0 = W_e[j];
  const float we1 = W_e[HIDDEN + j];
  const float be = b_e[j];
  const int* __restrict__ srcs = ei;
  const int* __restrict__ dsts = ei + N_EDGES;
  const float2* __restrict__ ea2 = (const float2*)ea;
  for (int e = blockIdx.x * 2 + g; e < N_EDGES; e += gridDim.x * 2) {
    const int s = srcs[e];
    const int d = dsts[e];
    const float2 a = ea2[e];
    float m = h[s * HIDDEN + j] + fmaf(a.x, we0, fmaf(a.y, we1, be));
    m = m > 0.f ? m : 0.f;
    unsafeAtomicAdd(&agg[d * HIDDEN + j], m);
  }
}

// ---------------------------------------------------------------------------
// MLP: out = [relu]( relu(z@W1+b1) @ W2 + b2 );  z = zbuf (+ agg if ADD_AGG)
// ---------------------------------------------------------------------------
template <bool RELU_OUT, bool ADD_AGG>
__global__ __launch_bounds__(256) void mlp_kernel(
    const float* __restrict__ zbuf, const float* __restrict__ agg,
    const float* __restrict__ W1, const float* __restrict__ b1,
    const float* __restrict__ W2, const float* __restrict__ b2,
    float* __restrict__ out) {
  const int NB = 32;
  const int NT = 16;
  __shared__ float zs[NB][HIDDEN];
  __shared__ float ts[NB][HIDDEN];
  const int j = threadIdx.x & 127;
  const int g = threadIdx.x >> 7;
  const int n0 = blockIdx.x * NB;

#pragma unroll
  for (int n = 0; n < NT; ++n) {
    const int nn = g * NT + n;
    float v = zbuf[(n0 + nn) * HIDDEN + j];
    if (ADD_AGG) v += agg[(n0 + nn) * HIDDEN + j];
    zs[nn][j] = v;
  }
  __syncthreads();

  float acc[NT];
  const float b1j = b1[j];
#pragma unroll
  for (int n = 0; n < NT; ++n) acc[n] = b1j;
  for (int k = 0; k < HIDDEN; k += 4) {
    const float w0 = W1[(k + 0) * HIDDEN + j];
    const float w1 = W1[(k + 1) * HIDDEN + j];
    const float w2 = W1[(k + 2) * HIDDEN + j];
    const float w3 = W1[(k + 3) * HIDDEN + j];
#pragma unroll
    for (int n = 0; n < NT; ++n) {
      const float4 z = *reinterpret_cast<const float4*>(&zs[g * NT + n][k]);
      acc[n] = fmaf(z.x, w0, acc[n]);
      acc[n] = fmaf(z.y, w1, acc[n]);
      acc[n] = fmaf(z.z, w2, acc[n]);
      acc[n] = fmaf(z.w, w3, acc[n]);
    }
  }
#pragma unroll
  for (int n = 0; n < NT; ++n) ts[g * NT + n][j] = acc[n] > 0.f ? acc[n] : 0.f;
  __syncthreads();

  const float b2j = b2[j];
#pragma unroll
  for (int n = 0; n < NT; ++n) acc[n] = b2j;
  for (int k = 0; k < HIDDEN; k += 4) {
    const float w0 = W2[(k + 0) * HIDDEN + j];
    const float w1 = W2[(k + 1) * HIDDEN + j];
    const float w2 = W2[(k + 2) * HIDDEN + j];
    const float w3 = W2[(k + 3) * HIDDEN + j];
#pragma unroll
    for (int n = 0; n < NT; ++n) {
      const float4 z = *reinterpret_cast<const float4*>(&ts[g * NT + n][k]);
      acc[n] = fmaf(z.x, w0, acc[n]);
      acc[n] = fmaf(z.y, w1, acc[n]);
      acc[n] = fmaf(z.z, w2, acc[n]);
      acc[n] = fmaf(z.w, w3, acc[n]);
    }
  }
#pragma unroll
  for (int n = 0; n < NT; ++n) {
    float v = acc[n];
    if (RELU_OUT) v = v > 0.f ? v : 0.f;
    out[(n0 + g * NT + n) * HIDDEN + j] = v;
  }
}

extern "C" void kernel_launch(void* const* d_in, const int* in_sizes, int n_in,
                              void* d_out, int out_size, void* d_ws, size_t ws_size,
                              hipStream_t stream) {
  const float* x    = (const float*)d_in[0];
  const int*   ei   = (const int*)d_in[1];
  const float* ea   = (const float*)d_in[2];
  const float* W_in = (const float*)d_in[3];
  const float* b_in = (const float*)d_in[4];
  const float* W_e  = (const float*)d_in[5];
  const float* b_e  = (const float*)d_in[6];
  const float* W1   = (const float*)d_in[7];
  const float* b1   = (const float*)d_in[8];
  const float* W2   = (const float*)d_in[9];
  const float* b2   = (const float*)d_in[10];

  const int* srcs = ei;
  const int* dsts = ei + N_EDGES;
  const float2* ea2 = (const float2*)ea;

  float* h = (float*)d_out;  // node features, rewritten in place per stage
  char* ws = (char*)d_ws;

  // ws layout (new path)
  const size_t DEG_OFF  = 0;                       // 400000 B
  const size_t OFF_OFF  = 512 * 1024;              // 400000 B
  const size_t CUR_OFF  = 1024 * 1024;             // 400000 B
  const size_t BSUM_OFF = 1536 * 1024;             // 1564 B
  const size_t BOFF_OFF = 1536 * 1024 + 4096;      // 1564 B
  const size_t PSRC_OFF = 2 * 1024 * 1024;         // 6.4 MB
  const size_t PEA_OFF  = 8704 * 1024;             // 12.8 MB
  const size_t Z_OFF    = 22 * 1024 * 1024;        // 51.2 MB
  const size_t need = Z_OFF + (size_t)N_NODES * HIDDEN * sizeof(float);

  // h0 = x @ W_in + b_in
  node_init_kernel<<<2048, 256, 0, stream>>>(x, W_in, b_in, h);

  if (ws_size >= need) {
    int* deg    = (int*)(ws + DEG_OFF);
    int* off    = (int*)(ws + OFF_OFF);
    int* cursor = (int*)(ws + CUR_OFF);
    int* bsum   = (int*)(ws + BSUM_OFF);
    int* boff   = (int*)(ws + BOFF_OFF);
    int* psrc   = (int*)(ws + PSRC_OFF);
    float2* pea = (float2*)(ws + PEA_OFF);
    float* z    = (float*)(ws + Z_OFF);

    // ---- CSR build (once, reused by both convs) ----
    hipMemsetAsync(deg, 0, N_NODES * sizeof(int), stream);
    k_hist<<<(N_EDGES + 255) / 256, 256, 0, stream>>>(dsts, deg);
    k_chunk_sum<<<NCHUNK, 256, 0, stream>>>(deg, bsum);
    k_scan_bsum<<<1, 512, 0, stream>>>(bsum, boff);
    k_off<<<NCHUNK, 256, 0, stream>>>(deg, boff, off, cursor);
    k_fill<<<(N_EDGES + 255) / 256, 256, 0, stream>>>(srcs, dsts, ea2, cursor, psrc, pea);

    // ---- conv1 ----
    gather_z_kernel<<<4096, 256, 0, stream>>>(off, deg, psrc, pea, W_e, b_e, h, z);
    mlp_kernel<true, false><<<N_NODES / 32, 256, 0, stream>>>(z, nullptr, W1, b1, W2, b2, h);

    // ---- conv2 ----
    gather_z_kernel<<<4096, 256, 0, stream>>>(off, deg, psrc, pea, W_e, b_e, h, z);
    mlp_kernel<false, false><<<N_NODES / 32, 256, 0, stream>>>(z, nullptr, W1, b1, W2, b2, h);
  } else {
    // Fallback: atomic scatter path (round-1 behavior)
    float* agg = (float*)d_ws;
    const size_t agg_bytes = (size_t)N_NODES * HIDDEN * sizeof(float);

    hipMemsetAsync(agg, 0, agg_bytes, stream);
    edge_scatter_kernel<<<4096, 256, 0, stream>>>(ei, ea, W_e, b_e, h, agg);
    mlp_kernel<true, true><<<N_NODES / 32, 256, 0, stream>>>(h, agg, W1, b1, W2, b2, h);

    hipMemsetAsync(agg, 0, agg_bytes, stream);
    edge_scatter_kernel<<<4096, 256, 0, stream>>>(ei, ea, W_e, b_e, h, agg);
    mlp_kernel<false, true><<<N_NODES / 32, 256, 0, stream>>>(h, agg, W1, b1, W2, b2, h);
  }
}

// Round 3
// 502.999 us; speedup vs baseline: 3.3627x; 1.7363x over previous
//
#include <hip/hip_runtime.h>

#define N_NODES 100000
#define N_EDGES 1600000
#define NODE_DIM 24
#define HIDDEN 128
#define NCHUNK 391  // ceil(N_NODES/256)

typedef __attribute__((ext_vector_type(8))) short bf16x8;
typedef __attribute__((ext_vector_type(4))) float f32x4;

__device__ __forceinline__ ushort f2bf(float f) {
  uint u = __builtin_bit_cast(uint, f);
  u += 0x7fffu + ((u >> 16) & 1u);  // RTNE
  return (ushort)(u >> 16);
}
__device__ __forceinline__ float bflo(uint v) { return __builtin_bit_cast(float, v << 16); }
__device__ __forceinline__ float bfhi(uint v) { return __builtin_bit_cast(float, v & 0xffff0000u); }

// ---------------------------------------------------------------------------
// K1: h[n][j] = b_in[j] + sum_d x[n][d] * W_in[d][j]; also bf16 mirror
// ---------------------------------------------------------------------------
__global__ __launch_bounds__(256) void node_init_kernel(
    const float* __restrict__ x, const float* __restrict__ W_in,
    const float* __restrict__ b_in, float* __restrict__ h,
    ushort* __restrict__ hb) {
  __shared__ float w_lds[NODE_DIM * HIDDEN];
  __shared__ float b_lds[HIDDEN];
  for (int i = threadIdx.x; i < NODE_DIM * HIDDEN; i += blockDim.x) w_lds[i] = W_in[i];
  if (threadIdx.x < HIDDEN) b_lds[threadIdx.x] = b_in[threadIdx.x];
  __syncthreads();
  const int j = threadIdx.x & 127;
  const int g = threadIdx.x >> 7;
  for (int n = blockIdx.x * 2 + g; n < N_NODES; n += gridDim.x * 2) {
    float acc = b_lds[j];
    const float* xr = x + (size_t)n * NODE_DIM;
#pragma unroll
    for (int d = 0; d < NODE_DIM; ++d) acc = fmaf(xr[d], w_lds[d * HIDDEN + j], acc);
    h[(size_t)n * HIDDEN + j] = acc;
    if (hb) hb[(size_t)n * HIDDEN + j] = f2bf(acc);
  }
}

// ---------------------------------------------------------------------------
// CSR build: histogram -> scan -> permute fill
// ---------------------------------------------------------------------------
__global__ __launch_bounds__(256) void k_hist(const int* __restrict__ dsts,
                                              int* __restrict__ deg) {
  int e = blockIdx.x * 256 + threadIdx.x;
  if (e < N_EDGES) atomicAdd(&deg[dsts[e]], 1);
}

__global__ __launch_bounds__(256) void k_chunk_sum(const int* __restrict__ deg,
                                                   int* __restrict__ bsum) {
  __shared__ int s[256];
  int n = blockIdx.x * 256 + threadIdx.x;
  s[threadIdx.x] = (n < N_NODES) ? deg[n] : 0;
  __syncthreads();
  for (int d = 128; d > 0; d >>= 1) {
    if (threadIdx.x < d) s[threadIdx.x] += s[threadIdx.x + d];
    __syncthreads();
  }
  if (threadIdx.x == 0) bsum[blockIdx.x] = s[0];
}

__global__ __launch_bounds__(512) void k_scan_bsum(const int* __restrict__ bsum,
                                                   int* __restrict__ boff) {
  __shared__ int s[512];
  const int t = threadIdx.x;
  int v = (t < NCHUNK) ? bsum[t] : 0;
  s[t] = v;
  __syncthreads();
  for (int d = 1; d < 512; d <<= 1) {
    int x = (t >= d) ? s[t - d] : 0;
    __syncthreads();
    s[t] += x;
    __syncthreads();
  }
  if (t < NCHUNK) boff[t] = s[t] - v;  // exclusive
}

__global__ __launch_bounds__(256) void k_off(const int* __restrict__ deg,
                                             const int* __restrict__ boff,
                                             int* __restrict__ off,
                                             int* __restrict__ cursor) {
  __shared__ int s[256];
  const int t = threadIdx.x;
  int n = blockIdx.x * 256 + t;
  int v = (n < N_NODES) ? deg[n] : 0;
  s[t] = v;
  __syncthreads();
  for (int d = 1; d < 256; d <<= 1) {
    int x = (t >= d) ? s[t - d] : 0;
    __syncthreads();
    s[t] += x;
    __syncthreads();
  }
  if (n < N_NODES) {
    int o = boff[blockIdx.x] + s[t] - v;
    off[n] = o;
    cursor[n] = o;
  }
}

__global__ __launch_bounds__(256) void k_fill(const int* __restrict__ srcs,
                                              const int* __restrict__ dsts,
                                              const float2* __restrict__ ea2,
                                              int* __restrict__ cursor,
                                              int* __restrict__ psrc,
                                              float2* __restrict__ pea) {
  int e = blockIdx.x * 256 + threadIdx.x;
  if (e < N_EDGES) {
    int pos = atomicAdd(&cursor[dsts[e]], 1);
    psrc[pos] = srcs[e];
    pea[pos] = ea2[e];
  }
}

// ---------------------------------------------------------------------------
// Weight prep: W1t/W2t[n][k] = bf16(W[k][n])  (col-major transposed, bf16)
// ---------------------------------------------------------------------------
__global__ __launch_bounds__(256) void k_wprep(const float* __restrict__ W1,
                                               const float* __restrict__ W2,
                                               ushort* __restrict__ W1t,
                                               ushort* __restrict__ W2t) {
  int i = blockIdx.x * 256 + threadIdx.x;
  if (i < HIDDEN * HIDDEN) {
    int k = i >> 7, n = i & 127;
    W1t[n * HIDDEN + k] = f2bf(W1[k * HIDDEN + n]);
    W2t[n * HIDDEN + k] = f2bf(W2[k * HIDDEN + n]);
  }
}

// ---------------------------------------------------------------------------
// Gather: z[n] = h[n] + sum_{e: dst=n} relu(hb[src_e] + We*ea_e + be), bf16 out
// one wave per node; hb rows are 256B coalesced (64 lanes x dword)
// ---------------------------------------------------------------------------
__global__ __launch_bounds__(256) void gather_z_bf16(
    const int* __restrict__ off, const int* __restrict__ deg,
    const int* __restrict__ psrc, const float2* __restrict__ pea,
    const float* __restrict__ W_e, const float* __restrict__ b_e,
    const float* __restrict__ hf, const uint* __restrict__ hb32,
    uint* __restrict__ zb32) {
  const int wave = threadIdx.x >> 6;
  const int lane = threadIdx.x & 63;
  const int n = blockIdx.x * 4 + wave;
  if (n >= N_NODES) return;
  const int j0 = lane * 2;
  const float we00 = W_e[j0], we01 = W_e[j0 + 1];
  const float we10 = W_e[HIDDEN + j0], we11 = W_e[HIDDEN + j0 + 1];
  const float eb0 = b_e[j0], eb1 = b_e[j0 + 1];
  const float2 hself = ((const float2*)(hf + (size_t)n * HIDDEN))[lane];
  float acc0 = hself.x, acc1 = hself.y;
  const int o = off[n];
  const int d = deg[n];
  int t = 0;
  for (; t + 2 <= d; t += 2) {
    const int s0 = psrc[o + t], s1 = psrc[o + t + 1];
    const float2 a0 = pea[o + t], a1 = pea[o + t + 1];
    const uint v0 = hb32[(size_t)s0 * 64 + lane];
    const uint v1 = hb32[(size_t)s1 * 64 + lane];
    const float m00 = bflo(v0) + fmaf(a0.x, we00, fmaf(a0.y, we10, eb0));
    const float m01 = bfhi(v0) + fmaf(a0.x, we01, fmaf(a0.y, we11, eb1));
    const float m10 = bflo(v1) + fmaf(a1.x, we00, fmaf(a1.y, we10, eb0));
    const float m11 = bfhi(v1) + fmaf(a1.x, we01, fmaf(a1.y, we11, eb1));
    acc0 += fmaxf(m00, 0.f) + fmaxf(m10, 0.f);
    acc1 += fmaxf(m01, 0.f) + fmaxf(m11, 0.f);
  }
  if (t < d) {
    const int s0 = psrc[o + t];
    const float2 a0 = pea[o + t];
    const uint v0 = hb32[(size_t)s0 * 64 + lane];
    const float m00 = bflo(v0) + fmaf(a0.x, we00, fmaf(a0.y, we10, eb0));
    const float m01 = bfhi(v0) + fmaf(a0.x, we01, fmaf(a0.y, we11, eb1));
    acc0 += fmaxf(m00, 0.f);
    acc1 += fmaxf(m01, 0.f);
  }
  zb32[(size_t)n * 64 + lane] = (uint)f2bf(acc0) | ((uint)f2bf(acc1) << 16);
}

// ---------------------------------------------------------------------------
// MFMA MLP: out = [relu]( relu(z@W1+b1) @ W2 + b2 ), z bf16, f32 accum
// block = 256 thr = 4 waves; 64 nodes/block; wave w owns cols [32w,32w+32)
// ---------------------------------------------------------------------------
__global__ __launch_bounds__(256) void mlp_mfma(
    const ushort* __restrict__ zb, const ushort* __restrict__ W1t,
    const ushort* __restrict__ W2t, const float* __restrict__ bias1,
    const float* __restrict__ bias2, float* __restrict__ out,
    ushort* __restrict__ hbout, const int relu_out) {
  __shared__ short zs[64][136];
  __shared__ short ts[64][136];
  const int tid = threadIdx.x;
  const int lane = tid & 63;
  const int wave = tid >> 6;
  const int n0 = blockIdx.x * 64;
  const int nrows = (N_NODES - n0 < 64) ? (N_NODES - n0) : 64;

  for (int c = tid; c < 1024; c += 256) {
    const int r = c >> 4;
    const int k = (c & 15) << 3;
    bf16x8 v = (bf16x8)(short)0;
    if (r < nrows) v = *(const bf16x8*)&zb[(size_t)(n0 + r) * HIDDEN + k];
    *(bf16x8*)&zs[r][k] = v;
  }
  __syncthreads();

  const int l15 = lane & 15;
  const int kq = lane >> 4;  // 0..3
  const int colbase = wave * 32;
  const int c0 = colbase + l15, c1 = colbase + 16 + l15;

  f32x4 acc[4][2];
  {
    const float bb0 = bias1[c0], bb1 = bias1[c1];
#pragma unroll
    for (int mt = 0; mt < 4; ++mt) {
      acc[mt][0] = (f32x4){bb0, bb0, bb0, bb0};
      acc[mt][1] = (f32x4){bb1, bb1, bb1, bb1};
    }
  }
#pragma unroll
  for (int kt = 0; kt < 4; ++kt) {
    const int kk = kt * 32 + kq * 8;
    const bf16x8 bf0 = *(const bf16x8*)&W1t[(size_t)c0 * HIDDEN + kk];
    const bf16x8 bf1 = *(const bf16x8*)&W1t[(size_t)c1 * HIDDEN + kk];
#pragma unroll
    for (int mt = 0; mt < 4; ++mt) {
      const bf16x8 a = *(const bf16x8*)&zs[mt * 16 + l15][kk];
      acc[mt][0] = __builtin_amdgcn_mfma_f32_16x16x32_bf16(a, bf0, acc[mt][0], 0, 0, 0);
      acc[mt][1] = __builtin_amdgcn_mfma_f32_16x16x32_bf16(a, bf1, acc[mt][1], 0, 0, 0);
    }
  }
  // relu -> ts (bf16)
#pragma unroll
  for (int mt = 0; mt < 4; ++mt)
#pragma unroll
    for (int nt = 0; nt < 2; ++nt)
#pragma unroll
      for (int r = 0; r < 4; ++r) {
        const int row = mt * 16 + kq * 4 + r;
        const int col = colbase + nt * 16 + l15;
        float v = acc[mt][nt][r];
        ts[row][col] = (short)f2bf(v > 0.f ? v : 0.f);
      }
  __syncthreads();

  // layer 2
  {
    const float bb0 = bias2[c0], bb1 = bias2[c1];
#pragma unroll
    for (int mt = 0; mt < 4; ++mt) {
      acc[mt][0] = (f32x4){bb0, bb0, bb0, bb0};
      acc[mt][1] = (f32x4){bb1, bb1, bb1, bb1};
    }
  }
#pragma unroll
  for (int kt = 0; kt < 4; ++kt) {
    const int kk = kt * 32 + kq * 8;
    const bf16x8 bf0 = *(const bf16x8*)&W2t[(size_t)c0 * HIDDEN + kk];
    const bf16x8 bf1 = *(const bf16x8*)&W2t[(size_t)c1 * HIDDEN + kk];
#pragma unroll
    for (int mt = 0; mt < 4; ++mt) {
      const bf16x8 a = *(const bf16x8*)&ts[mt * 16 + l15][kk];
      acc[mt][0] = __builtin_amdgcn_mfma_f32_16x16x32_bf16(a, bf0, acc[mt][0], 0, 0, 0);
      acc[mt][1] = __builtin_amdgcn_mfma_f32_16x16x32_bf16(a, bf1, acc[mt][1], 0, 0, 0);
    }
  }
  // epilogue
#pragma unroll
  for (int mt = 0; mt < 4; ++mt)
#pragma unroll
    for (int nt = 0; nt < 2; ++nt)
#pragma unroll
      for (int r = 0; r < 4; ++r) {
        const int row = mt * 16 + kq * 4 + r;
        if (row < nrows) {
          const int col = colbase + nt * 16 + l15;
          float v = acc[mt][nt][r];
          if (relu_out) v = v > 0.f ? v : 0.f;
          out[(size_t)(n0 + row) * HIDDEN + col] = v;
          if (hbout) hbout[(size_t)(n0 + row) * HIDDEN + col] = f2bf(v);
        }
      }
}

// ---------------------------------------------------------------------------
// Fallback path (atomic scatter + f32 MLP), used only if ws too small
// ---------------------------------------------------------------------------
__global__ __launch_bounds__(256) void edge_scatter_kernel(
    const int* __restrict__ ei, const float* __restrict__ ea,
    const float* __restrict__ W_e, const float* __restrict__ b_e,
    const float* __restrict__ h, float* __restrict__ agg) {
  const int j = threadIdx.x & 127;
  const int g = threadIdx.x >> 7;
  const float we0 = W_e[j];
  const float we1 = W_e[HIDDEN + j];
  const float be = b_e[j];
  const int* __restrict__ srcs = ei;
  const int* __restrict__ dsts = ei + N_EDGES;
  const float2* __restrict__ ea2 = (const float2*)ea;
  for (int e = blockIdx.x * 2 + g; e < N_EDGES; e += gridDim.x * 2) {
    const int s = srcs[e];
    const int d = dsts[e];
    const float2 a = ea2[e];
    float m = h[(size_t)s * HIDDEN + j] + fmaf(a.x, we0, fmaf(a.y, we1, be));
    m = m > 0.f ? m : 0.f;
    unsafeAtomicAdd(&agg[(size_t)d * HIDDEN + j], m);
  }
}

template <bool RELU_OUT>
__global__ __launch_bounds__(256) void mlp_f32_kernel(
    const float* __restrict__ zbuf, const float* __restrict__ agg,
    const float* __restrict__ W1, const float* __restrict__ b1,
    const float* __restrict__ W2, const float* __restrict__ b2,
    float* __restrict__ out) {
  const int NB = 32;
  const int NT = 16;
  __shared__ float zs[NB][HIDDEN];
  __shared__ float ts[NB][HIDDEN];
  const int j = threadIdx.x & 127;
  const int g = threadIdx.x >> 7;
  const int n0 = blockIdx.x * NB;

#pragma unroll
  for (int n = 0; n < NT; ++n) {
    const int nn = g * NT + n;
    zs[nn][j] = zbuf[(size_t)(n0 + nn) * HIDDEN + j] + agg[(size_t)(n0 + nn) * HIDDEN + j];
  }
  __syncthreads();

  float acc[NT];
  const float b1j = b1[j];
#pragma unroll
  for (int n = 0; n < NT; ++n) acc[n] = b1j;
  for (int k = 0; k < HIDDEN; k += 4) {
    const float w0 = W1[(k + 0) * HIDDEN + j];
    const float w1 = W1[(k + 1) * HIDDEN + j];
    const float w2 = W1[(k + 2) * HIDDEN + j];
    const float w3 = W1[(k + 3) * HIDDEN + j];
#pragma unroll
    for (int n = 0; n < NT; ++n) {
      const float4 z = *reinterpret_cast<const float4*>(&zs[g * NT + n][k]);
      acc[n] = fmaf(z.x, w0, acc[n]);
      acc[n] = fmaf(z.y, w1, acc[n]);
      acc[n] = fmaf(z.z, w2, acc[n]);
      acc[n] = fmaf(z.w, w3, acc[n]);
    }
  }
#pragma unroll
  for (int n = 0; n < NT; ++n) ts[g * NT + n][j] = acc[n] > 0.f ? acc[n] : 0.f;
  __syncthreads();

  const float b2j = b2[j];
#pragma unroll
  for (int n = 0; n < NT; ++n) acc[n] = b2j;
  for (int k = 0; k < HIDDEN; k += 4) {
    const float w0 = W2[(k + 0) * HIDDEN + j];
    const float w1 = W2[(k + 1) * HIDDEN + j];
    const float w2 = W2[(k + 2) * HIDDEN + j];
    const float w3 = W2[(k + 3) * HIDDEN + j];
#pragma unroll
    for (int n = 0; n < NT; ++n) {
      const float4 z = *reinterpret_cast<const float4*>(&ts[g * NT + n][k]);
      acc[n] = fmaf(z.x, w0, acc[n]);
      acc[n] = fmaf(z.y, w1, acc[n]);
      acc[n] = fmaf(z.z, w2, acc[n]);
      acc[n] = fmaf(z.w, w3, acc[n]);
    }
  }
#pragma unroll
  for (int n = 0; n < NT; ++n) {
    float v = acc[n];
    if (RELU_OUT) v = v > 0.f ? v : 0.f;
    out[(size_t)(n0 + g * NT + n) * HIDDEN + j] = v;
  }
}

extern "C" void kernel_launch(void* const* d_in, const int* in_sizes, int n_in,
                              void* d_out, int out_size, void* d_ws, size_t ws_size,
                              hipStream_t stream) {
  const float* x    = (const float*)d_in[0];
  const int*   ei   = (const int*)d_in[1];
  const float* ea   = (const float*)d_in[2];
  const float* W_in = (const float*)d_in[3];
  const float* b_in = (const float*)d_in[4];
  const float* W_e  = (const float*)d_in[5];
  const float* b_e  = (const float*)d_in[6];
  const float* W1   = (const float*)d_in[7];
  const float* b1   = (const float*)d_in[8];
  const float* W2   = (const float*)d_in[9];
  const float* b2   = (const float*)d_in[10];

  const int* srcs = ei;
  const int* dsts = ei + N_EDGES;
  const float2* ea2 = (const float2*)ea;

  float* h = (float*)d_out;  // f32 node features (also final output)
  char* ws = (char*)d_ws;

  // ws layout
  const size_t DEG_OFF  = 0;           // 400000
  const size_t OFF_OFF  = 400000;      // 400000
  const size_t CUR_OFF  = 800000;      // 400000
  const size_t BSUM_OFF = 1200000;     // 1564
  const size_t BOFF_OFF = 1204224;     // 1564
  const size_t WT1_OFF  = 1310720;     // 32768
  const size_t WT2_OFF  = 1343488;     // 32768
  const size_t PSRC_OFF = 1572864;     // 6.4 MB
  const size_t PEA_OFF  = 8000000;     // 12.8 MB
  const size_t HB_OFF   = 20800000;    // 25.6 MB (bf16 h mirror)
  const size_t ZB_OFF   = 46400000;    // 25.6 MB (bf16 z)
  const size_t need = ZB_OFF + (size_t)N_NODES * HIDDEN * sizeof(ushort);

  if (ws_size >= need) {
    int* deg     = (int*)(ws + DEG_OFF);
    int* off     = (int*)(ws + OFF_OFF);
    int* cursor  = (int*)(ws + CUR_OFF);
    int* bsum    = (int*)(ws + BSUM_OFF);
    int* boff    = (int*)(ws + BOFF_OFF);
    ushort* W1t  = (ushort*)(ws + WT1_OFF);
    ushort* W2t  = (ushort*)(ws + WT2_OFF);
    int* psrc    = (int*)(ws + PSRC_OFF);
    float2* pea  = (float2*)(ws + PEA_OFF);
    ushort* hb   = (ushort*)(ws + HB_OFF);
    ushort* zb   = (ushort*)(ws + ZB_OFF);

    node_init_kernel<<<2048, 256, 0, stream>>>(x, W_in, b_in, h, hb);

    // CSR build (reused by both convs)
    hipMemsetAsync(deg, 0, N_NODES * sizeof(int), stream);
    k_hist<<<(N_EDGES + 255) / 256, 256, 0, stream>>>(dsts, deg);
    k_chunk_sum<<<NCHUNK, 256, 0, stream>>>(deg, bsum);
    k_scan_bsum<<<1, 512, 0, stream>>>(bsum, boff);
    k_off<<<NCHUNK, 256, 0, stream>>>(deg, boff, off, cursor);
    k_fill<<<(N_EDGES + 255) / 256, 256, 0, stream>>>(srcs, dsts, ea2, cursor, psrc, pea);
    k_wprep<<<(HIDDEN * HIDDEN + 255) / 256, 256, 0, stream>>>(W1, W2, W1t, W2t);

    const int gblocks = (N_NODES + 3) / 4;
    const int mblocks = (N_NODES + 63) / 64;

    // conv1
    gather_z_bf16<<<gblocks, 256, 0, stream>>>(off, deg, psrc, pea, W_e, b_e,
                                               h, (const uint*)hb, (uint*)zb);
    mlp_mfma<<<mblocks, 256, 0, stream>>>(zb, W1t, W2t, b1, b2, h, hb, 1);

    // conv2
    gather_z_bf16<<<gblocks, 256, 0, stream>>>(off, deg, psrc, pea, W_e, b_e,
                                               h, (const uint*)hb, (uint*)zb);
    mlp_mfma<<<mblocks, 256, 0, stream>>>(zb, W1t, W2t, b1, b2, h, nullptr, 0);
  } else {
    // Fallback: atomic scatter path
    float* agg = (float*)d_ws;
    const size_t agg_bytes = (size_t)N_NODES * HIDDEN * sizeof(float);

    node_init_kernel<<<2048, 256, 0, stream>>>(x, W_in, b_in, h, nullptr);

    hipMemsetAsync(agg, 0, agg_bytes, stream);
    edge_scatter_kernel<<<4096, 256, 0, stream>>>(ei, ea, W_e, b_e, h, agg);
    mlp_f32_kernel<true><<<N_NODES / 32, 256, 0, stream>>>(h, agg, W1, b1, W2, b2, h);

    hipMemsetAsync(agg, 0, agg_bytes, stream);
    edge_scatter_kernel<<<4096, 256, 0, stream>>>(ei, ea, W_e, b_e, h, agg);
    mlp_f32_kernel<false><<<N_NODES / 32, 256, 0, stream>>>(h, agg, W1, b1, W2, b2, h);
  }
}

// Round 4
// 470.331 us; speedup vs baseline: 3.5963x; 1.0695x over previous
//
#include <hip/hip_runtime.h>

#define N_NODES 100000
#define N_EDGES 1600000
#define NODE_DIM 24
#define HIDDEN 128
#define NCHUNK 391   // ceil(N_NODES/256)
#define BSHIFT 9     // 512 nodes per bucket
#define NBUCK 196    // ceil(100000/512)
#define P1_EDGES 2048

typedef __attribute__((ext_vector_type(8))) short bf16x8;
typedef __attribute__((ext_vector_type(4))) float f32x4;

__device__ __forceinline__ ushort f2bf(float f) {
  uint u = __builtin_bit_cast(uint, f);
  u += 0x7fffu + ((u >> 16) & 1u);  // RTNE
  return (ushort)(u >> 16);
}
__device__ __forceinline__ float bflo(uint v) { return __builtin_bit_cast(float, v << 16); }
__device__ __forceinline__ float bfhi(uint v) { return __builtin_bit_cast(float, v & 0xffff0000u); }

// ---------------------------------------------------------------------------
// K1: h[n][j] = b_in[j] + sum_d x[n][d] * W_in[d][j]; also bf16 mirror
// ---------------------------------------------------------------------------
__global__ __launch_bounds__(256) void node_init_kernel(
    const float* __restrict__ x, const float* __restrict__ W_in,
    const float* __restrict__ b_in, float* __restrict__ h,
    ushort* __restrict__ hb) {
  __shared__ float w_lds[NODE_DIM * HIDDEN];
  __shared__ float b_lds[HIDDEN];
  for (int i = threadIdx.x; i < NODE_DIM * HIDDEN; i += blockDim.x) w_lds[i] = W_in[i];
  if (threadIdx.x < HIDDEN) b_lds[threadIdx.x] = b_in[threadIdx.x];
  __syncthreads();
  const int j = threadIdx.x & 127;
  const int g = threadIdx.x >> 7;
  for (int n = blockIdx.x * 2 + g; n < N_NODES; n += gridDim.x * 2) {
    float acc = b_lds[j];
    const float* xr = x + (size_t)n * NODE_DIM;
#pragma unroll
    for (int d = 0; d < NODE_DIM; ++d) acc = fmaf(xr[d], w_lds[d * HIDDEN + j], acc);
    h[(size_t)n * HIDDEN + j] = acc;
    if (hb) hb[(size_t)n * HIDDEN + j] = f2bf(acc);
  }
}

// ---------------------------------------------------------------------------
// CSR degree/offsets
// ---------------------------------------------------------------------------
__global__ __launch_bounds__(256) void k_hist(const int* __restrict__ dsts,
                                              int* __restrict__ deg) {
  int e = blockIdx.x * 256 + threadIdx.x;
  if (e < N_EDGES) atomicAdd(&deg[dsts[e]], 1);
}

__global__ __launch_bounds__(256) void k_chunk_sum(const int* __restrict__ deg,
                                                   int* __restrict__ bsum) {
  __shared__ int s[256];
  int n = blockIdx.x * 256 + threadIdx.x;
  s[threadIdx.x] = (n < N_NODES) ? deg[n] : 0;
  __syncthreads();
  for (int d = 128; d > 0; d >>= 1) {
    if (threadIdx.x < d) s[threadIdx.x] += s[threadIdx.x + d];
    __syncthreads();
  }
  if (threadIdx.x == 0) bsum[blockIdx.x] = s[0];
}

__global__ __launch_bounds__(512) void k_scan_bsum(const int* __restrict__ bsum,
                                                   int* __restrict__ boff) {
  __shared__ int s[512];
  const int t = threadIdx.x;
  int v = (t < NCHUNK) ? bsum[t] : 0;
  s[t] = v;
  __syncthreads();
  for (int d = 1; d < 512; d <<= 1) {
    int x = (t >= d) ? s[t - d] : 0;
    __syncthreads();
    s[t] += x;
    __syncthreads();
  }
  if (t < NCHUNK) boff[t] = s[t] - v;  // exclusive
}

__global__ __launch_bounds__(256) void k_off(const int* __restrict__ deg,
                                             const int* __restrict__ boff,
                                             int* __restrict__ off) {
  __shared__ int s[256];
  const int t = threadIdx.x;
  int n = blockIdx.x * 256 + t;
  int v = (n < N_NODES) ? deg[n] : 0;
  s[t] = v;
  __syncthreads();
  for (int d = 1; d < 256; d <<= 1) {
    int x = (t >= d) ? s[t - d] : 0;
    __syncthreads();
    s[t] += x;
    __syncthreads();
  }
  if (n < N_NODES) off[n] = boff[blockIdx.x] + s[t] - v;
}

__global__ __launch_bounds__(256) void k_gcur(const int* __restrict__ off,
                                              int* __restrict__ gcur) {
  const int b = threadIdx.x;
  if (b < NBUCK) gcur[b] = off[b << BSHIFT];
}

// ---------------------------------------------------------------------------
// Phase 1: bucket scatter. Each block groups its 2048 edges by dst-bucket in
// LDS, reserves contiguous per-bucket ranges (one global atomic per bucket),
// then writes grouped -> coalesced. Record: {src | dstlocal<<20, bf16 ea pair}
// ---------------------------------------------------------------------------
__global__ __launch_bounds__(256) void k_bucket_scatter(
    const int* __restrict__ srcs, const int* __restrict__ dsts,
    const float2* __restrict__ ea2, int* __restrict__ gcur,
    uint2* __restrict__ tmp) {
  __shared__ int hist[256];
  __shared__ int sc[256];
  __shared__ int lofs[256];
  __shared__ int base[256];
  __shared__ int cur2[256];
  __shared__ uint2 stage[P1_EDGES];
  __shared__ uchar stage_b[P1_EDGES];
  const int t = threadIdx.x;
  const int e0 = blockIdx.x * P1_EDGES;

  hist[t] = 0;
  cur2[t] = 0;
  __syncthreads();

  uint rw0[8], rw1[8];
  int rb[8];
#pragma unroll
  for (int i = 0; i < 8; ++i) {
    const int e = e0 + t + i * 256;
    if (e < N_EDGES) {
      const int s = srcs[e];
      const int d = dsts[e];
      const float2 a = ea2[e];
      const int b = d >> BSHIFT;
      rb[i] = b;
      rw0[i] = (uint)s | ((uint)(d & 511) << 20);
      rw1[i] = (uint)f2bf(a.x) | ((uint)f2bf(a.y) << 16);
      atomicAdd(&hist[b], 1);
    } else {
      rb[i] = -1;
    }
  }
  __syncthreads();

  // exclusive scan of hist
  int v = hist[t];
  sc[t] = v;
  __syncthreads();
  for (int d = 1; d < 256; d <<= 1) {
    int x = (t >= d) ? sc[t - d] : 0;
    __syncthreads();
    sc[t] += x;
    __syncthreads();
  }
  lofs[t] = sc[t] - v;
  base[t] = (t < NBUCK && v > 0) ? atomicAdd(&gcur[t], v) : 0;
  __syncthreads();

  // stage grouped by bucket
#pragma unroll
  for (int i = 0; i < 8; ++i) {
    if (rb[i] >= 0) {
      const int l = atomicAdd(&cur2[rb[i]], 1);
      const int slot = lofs[rb[i]] + l;
      stage[slot] = make_uint2(rw0[i], rw1[i]);
      stage_b[slot] = (uchar)rb[i];
    }
  }
  __syncthreads();

  // coalesced copy-out
  const int total = (N_EDGES - e0 < P1_EDGES) ? (N_EDGES - e0) : P1_EDGES;
  for (int s = t; s < total; s += 256) {
    const int b = stage_b[s];
    tmp[base[b] + (s - lofs[b])] = stage[s];
  }
}

// ---------------------------------------------------------------------------
// Phase 2: per-bucket counting sort into final CSR order. One block per
// bucket; LDS cursors; writes confined to a ~64KB contiguous region.
// ---------------------------------------------------------------------------
__global__ __launch_bounds__(256) void k_bucket_sort(
    const uint2* __restrict__ tmp, const int* __restrict__ off,
    uint2* __restrict__ rec) {
  __shared__ int lcur[512];
  const int b = blockIdx.x;
  const int nb0 = b << BSHIFT;
  for (int i = threadIdx.x; i < 512; i += 256) {
    const int n = nb0 + i;
    lcur[i] = (n < N_NODES) ? off[n] : 0;
  }
  __syncthreads();
  const int s0 = off[nb0];
  const int s1 = (nb0 + 512 >= N_NODES) ? N_EDGES : off[nb0 + 512];
  for (int s = s0 + threadIdx.x; s < s1; s += 256) {
    const uint2 r = tmp[s];
    const int dl = (r.x >> 20) & 511;
    const int p = atomicAdd(&lcur[dl], 1);
    rec[p] = make_uint2(r.x & 0xFFFFFu, r.y);
  }
}

// ---------------------------------------------------------------------------
// Weight prep: W1t/W2t[n][k] = bf16(W[k][n])
// ---------------------------------------------------------------------------
__global__ __launch_bounds__(256) void k_wprep(const float* __restrict__ W1,
                                               const float* __restrict__ W2,
                                               ushort* __restrict__ W1t,
                                               ushort* __restrict__ W2t) {
  int i = blockIdx.x * 256 + threadIdx.x;
  if (i < HIDDEN * HIDDEN) {
    int k = i >> 7, n = i & 127;
    W1t[n * HIDDEN + k] = f2bf(W1[k * HIDDEN + n]);
    W2t[n * HIDDEN + k] = f2bf(W2[k * HIDDEN + n]);
  }
}

// ---------------------------------------------------------------------------
// Fused conv: per 64-node tile, gather z into LDS then MFMA 2-layer MLP.
// wave w gathers nodes [w*16, w*16+16); lane covers 2 feature cols.
// ---------------------------------------------------------------------------
__global__ __launch_bounds__(256) void conv_fused(
    const int* __restrict__ off, const int* __restrict__ deg,
    const uint2* __restrict__ rec, const float* __restrict__ W_e,
    const float* __restrict__ b_e, const float* __restrict__ hf,
    const uint* __restrict__ hb32, const ushort* __restrict__ W1t,
    const ushort* __restrict__ W2t, const float* __restrict__ bias1,
    const float* __restrict__ bias2, float* __restrict__ out,
    ushort* __restrict__ hbout, const int relu_out) {
  __shared__ short zs[64][136];
  __shared__ short ts[64][136];
  const int tid = threadIdx.x;
  const int lane = tid & 63;
  const int wave = tid >> 6;
  const int n0 = blockIdx.x * 64;
  const int nrows = (N_NODES - n0 < 64) ? (N_NODES - n0) : 64;

  // ---- gather phase ----
  {
    const int j0 = lane * 2;
    const float we00 = W_e[j0], we01 = W_e[j0 + 1];
    const float we10 = W_e[HIDDEN + j0], we11 = W_e[HIDDEN + j0 + 1];
    const float eb0 = b_e[j0], eb1 = b_e[j0 + 1];
    for (int i = 0; i < 16; ++i) {
      const int n = n0 + wave * 16 + i;
      uint packed = 0;
      if (n < N_NODES) {
        const float2 hs = ((const float2*)(hf + (size_t)n * HIDDEN))[lane];
        float a0 = hs.x, a1 = hs.y;
        const int o = off[n];
        const int dn = deg[n];
        int t2 = 0;
        for (; t2 + 4 <= dn; t2 += 4) {
          const uint2 r0 = rec[o + t2], r1 = rec[o + t2 + 1];
          const uint2 r2 = rec[o + t2 + 2], r3 = rec[o + t2 + 3];
          const uint v0 = hb32[(size_t)r0.x * 64 + lane];
          const uint v1 = hb32[(size_t)r1.x * 64 + lane];
          const uint v2 = hb32[(size_t)r2.x * 64 + lane];
          const uint v3 = hb32[(size_t)r3.x * 64 + lane];
          const float m00 = bflo(v0) + fmaf(bflo(r0.y), we00, fmaf(bfhi(r0.y), we10, eb0));
          const float m01 = bfhi(v0) + fmaf(bflo(r0.y), we01, fmaf(bfhi(r0.y), we11, eb1));
          const float m10 = bflo(v1) + fmaf(bflo(r1.y), we00, fmaf(bfhi(r1.y), we10, eb0));
          const float m11 = bfhi(v1) + fmaf(bflo(r1.y), we01, fmaf(bfhi(r1.y), we11, eb1));
          const float m20 = bflo(v2) + fmaf(bflo(r2.y), we00, fmaf(bfhi(r2.y), we10, eb0));
          const float m21 = bfhi(v2) + fmaf(bflo(r2.y), we01, fmaf(bfhi(r2.y), we11, eb1));
          const float m30 = bflo(v3) + fmaf(bflo(r3.y), we00, fmaf(bfhi(r3.y), we10, eb0));
          const float m31 = bfhi(v3) + fmaf(bflo(r3.y), we01, fmaf(bfhi(r3.y), we11, eb1));
          a0 += (fmaxf(m00, 0.f) + fmaxf(m10, 0.f)) + (fmaxf(m20, 0.f) + fmaxf(m30, 0.f));
          a1 += (fmaxf(m01, 0.f) + fmaxf(m11, 0.f)) + (fmaxf(m21, 0.f) + fmaxf(m31, 0.f));
        }
        for (; t2 < dn; ++t2) {
          const uint2 r0 = rec[o + t2];
          const uint v0 = hb32[(size_t)r0.x * 64 + lane];
          const float m00 = bflo(v0) + fmaf(bflo(r0.y), we00, fmaf(bfhi(r0.y), we10, eb0));
          const float m01 = bfhi(v0) + fmaf(bflo(r0.y), we01, fmaf(bfhi(r0.y), we11, eb1));
          a0 += fmaxf(m00, 0.f);
          a1 += fmaxf(m01, 0.f);
        }
        packed = (uint)f2bf(a0) | ((uint)f2bf(a1) << 16);
      }
      *(uint*)&zs[wave * 16 + i][lane * 2] = packed;
    }
  }
  __syncthreads();

  // ---- MLP phase (MFMA) ----
  const int l15 = lane & 15;
  const int kq = lane >> 4;
  const int colbase = wave * 32;
  const int c0 = colbase + l15, c1 = colbase + 16 + l15;

  f32x4 acc[4][2];
  {
    const float bb0 = bias1[c0], bb1 = bias1[c1];
#pragma unroll
    for (int mt = 0; mt < 4; ++mt) {
      acc[mt][0] = (f32x4){bb0, bb0, bb0, bb0};
      acc[mt][1] = (f32x4){bb1, bb1, bb1, bb1};
    }
  }
#pragma unroll
  for (int kt = 0; kt < 4; ++kt) {
    const int kk = kt * 32 + kq * 8;
    const bf16x8 bf0 = *(const bf16x8*)&W1t[(size_t)c0 * HIDDEN + kk];
    const bf16x8 bf1 = *(const bf16x8*)&W1t[(size_t)c1 * HIDDEN + kk];
#pragma unroll
    for (int mt = 0; mt < 4; ++mt) {
      const bf16x8 a = *(const bf16x8*)&zs[mt * 16 + l15][kk];
      acc[mt][0] = __builtin_amdgcn_mfma_f32_16x16x32_bf16(a, bf0, acc[mt][0], 0, 0, 0);
      acc[mt][1] = __builtin_amdgcn_mfma_f32_16x16x32_bf16(a, bf1, acc[mt][1], 0, 0, 0);
    }
  }
#pragma unroll
  for (int mt = 0; mt < 4; ++mt)
#pragma unroll
    for (int nt = 0; nt < 2; ++nt)
#pragma unroll
      for (int r = 0; r < 4; ++r) {
        const int row = mt * 16 + kq * 4 + r;
        const int col = colbase + nt * 16 + l15;
        float v = acc[mt][nt][r];
        ts[row][col] = (short)f2bf(v > 0.f ? v : 0.f);
      }
  __syncthreads();

  {
    const float bb0 = bias2[c0], bb1 = bias2[c1];
#pragma unroll
    for (int mt = 0; mt < 4; ++mt) {
      acc[mt][0] = (f32x4){bb0, bb0, bb0, bb0};
      acc[mt][1] = (f32x4){bb1, bb1, bb1, bb1};
    }
  }
#pragma unroll
  for (int kt = 0; kt < 4; ++kt) {
    const int kk = kt * 32 + kq * 8;
    const bf16x8 bf0 = *(const bf16x8*)&W2t[(size_t)c0 * HIDDEN + kk];
    const bf16x8 bf1 = *(const bf16x8*)&W2t[(size_t)c1 * HIDDEN + kk];
#pragma unroll
    for (int mt = 0; mt < 4; ++mt) {
      const bf16x8 a = *(const bf16x8*)&ts[mt * 16 + l15][kk];
      acc[mt][0] = __builtin_amdgcn_mfma_f32_16x16x32_bf16(a, bf0, acc[mt][0], 0, 0, 0);
      acc[mt][1] = __builtin_amdgcn_mfma_f32_16x16x32_bf16(a, bf1, acc[mt][1], 0, 0, 0);
    }
  }
#pragma unroll
  for (int mt = 0; mt < 4; ++mt)
#pragma unroll
    for (int nt = 0; nt < 2; ++nt)
#pragma unroll
      for (int r = 0; r < 4; ++r) {
        const int row = mt * 16 + kq * 4 + r;
        if (row < nrows) {
          const int col = colbase + nt * 16 + l15;
          float v = acc[mt][nt][r];
          if (relu_out) v = v > 0.f ? v : 0.f;
          out[(size_t)(n0 + row) * HIDDEN + col] = v;
          if (hbout) hbout[(size_t)(n0 + row) * HIDDEN + col] = f2bf(v);
        }
      }
}

// ---------------------------------------------------------------------------
// Fallback path (atomic scatter + f32 MLP), used only if ws too small
// ---------------------------------------------------------------------------
__global__ __launch_bounds__(256) void edge_scatter_kernel(
    const int* __restrict__ ei, const float* __restrict__ ea,
    const float* __restrict__ W_e, const float* __restrict__ b_e,
    const float* __restrict__ h, float* __restrict__ agg) {
  const int j = threadIdx.x & 127;
  const int g = threadIdx.x >> 7;
  const float we0 = W_e[j];
  const float we1 = W_e[HIDDEN + j];
  const float be = b_e[j];
  const int* __restrict__ srcs = ei;
  const int* __restrict__ dsts = ei + N_EDGES;
  const float2* __restrict__ ea2 = (const float2*)ea;
  for (int e = blockIdx.x * 2 + g; e < N_EDGES; e += gridDim.x * 2) {
    const int s = srcs[e];
    const int d = dsts[e];
    const float2 a = ea2[e];
    float m = h[(size_t)s * HIDDEN + j] + fmaf(a.x, we0, fmaf(a.y, we1, be));
    m = m > 0.f ? m : 0.f;
    unsafeAtomicAdd(&agg[(size_t)d * HIDDEN + j], m);
  }
}

template <bool RELU_OUT>
__global__ __launch_bounds__(256) void mlp_f32_kernel(
    const float* __restrict__ zbuf, const float* __restrict__ agg,
    const float* __restrict__ W1, const float* __restrict__ b1,
    const float* __restrict__ W2, const float* __restrict__ b2,
    float* __restrict__ out) {
  const int NB = 32;
  const int NT = 16;
  __shared__ float zs[NB][HIDDEN];
  __shared__ float ts[NB][HIDDEN];
  const int j = threadIdx.x & 127;
  const int g = threadIdx.x >> 7;
  const int n0 = blockIdx.x * NB;

#pragma unroll
  for (int n = 0; n < NT; ++n) {
    const int nn = g * NT + n;
    zs[nn][j] = zbuf[(size_t)(n0 + nn) * HIDDEN + j] + agg[(size_t)(n0 + nn) * HIDDEN + j];
  }
  __syncthreads();

  float acc[NT];
  const float b1j = b1[j];
#pragma unroll
  for (int n = 0; n < NT; ++n) acc[n] = b1j;
  for (int k = 0; k < HIDDEN; k += 4) {
    const float w0 = W1[(k + 0) * HIDDEN + j];
    const float w1 = W1[(k + 1) * HIDDEN + j];
    const float w2 = W1[(k + 2) * HIDDEN + j];
    const float w3 = W1[(k + 3) * HIDDEN + j];
#pragma unroll
    for (int n = 0; n < NT; ++n) {
      const float4 z = *reinterpret_cast<const float4*>(&zs[g * NT + n][k]);
      acc[n] = fmaf(z.x, w0, acc[n]);
      acc[n] = fmaf(z.y, w1, acc[n]);
      acc[n] = fmaf(z.z, w2, acc[n]);
      acc[n] = fmaf(z.w, w3, acc[n]);
    }
  }
#pragma unroll
  for (int n = 0; n < NT; ++n) ts[g * NT + n][j] = acc[n] > 0.f ? acc[n] : 0.f;
  __syncthreads();

  const float b2j = b2[j];
#pragma unroll
  for (int n = 0; n < NT; ++n) acc[n] = b2j;
  for (int k = 0; k < HIDDEN; k += 4) {
    const float w0 = W2[(k + 0) * HIDDEN + j];
    const float w1 = W2[(k + 1) * HIDDEN + j];
    const float w2 = W2[(k + 2) * HIDDEN + j];
    const float w3 = W2[(k + 3) * HIDDEN + j];
#pragma unroll
    for (int n = 0; n < NT; ++n) {
      const float4 z = *reinterpret_cast<const float4*>(&ts[g * NT + n][k]);
      acc[n] = fmaf(z.x, w0, acc[n]);
      acc[n] = fmaf(z.y, w1, acc[n]);
      acc[n] = fmaf(z.z, w2, acc[n]);
      acc[n] = fmaf(z.w, w3, acc[n]);
    }
  }
#pragma unroll
  for (int n = 0; n < NT; ++n) {
    float v = acc[n];
    if (RELU_OUT) v = v > 0.f ? v : 0.f;
    out[(size_t)(n0 + g * NT + n) * HIDDEN + j] = v;
  }
}

extern "C" void kernel_launch(void* const* d_in, const int* in_sizes, int n_in,
                              void* d_out, int out_size, void* d_ws, size_t ws_size,
                              hipStream_t stream) {
  const float* x    = (const float*)d_in[0];
  const int*   ei   = (const int*)d_in[1];
  const float* ea   = (const float*)d_in[2];
  const float* W_in = (const float*)d_in[3];
  const float* b_in = (const float*)d_in[4];
  const float* W_e  = (const float*)d_in[5];
  const float* b_e  = (const float*)d_in[6];
  const float* W1   = (const float*)d_in[7];
  const float* b1   = (const float*)d_in[8];
  const float* W2   = (const float*)d_in[9];
  const float* b2   = (const float*)d_in[10];

  const int* srcs = ei;
  const int* dsts = ei + N_EDGES;
  const float2* ea2 = (const float2*)ea;

  float* h = (float*)d_out;  // f32 node features (also final output)
  char* ws = (char*)d_ws;

  // ws layout. tmp (phase-1 output) is overlaid with hb_b: tmp is dead after
  // k_bucket_sort; hb_b is first written by conv1 (strictly later).
  const size_t DEG_OFF  = 0;                       // 400000
  const size_t OFF_OFF  = 400000;                  // 400000
  const size_t BSUM_OFF = 800000;                  // ~1.6KB
  const size_t BOFF_OFF = 804096;                  // ~1.6KB
  const size_t GCUR_OFF = 808192;                  // 784 B
  const size_t WT1_OFF  = 812288;                  // 32768
  const size_t WT2_OFF  = 845056;                  // 32768
  const size_t REC_OFF  = 1048576;                 // 12.8 MB final CSR records
  const size_t HBA_OFF  = REC_OFF + 12800000;      // 25.6 MB bf16 h (table A)
  const size_t TMP_OFF  = HBA_OFF + 25600000;      // 12.8 MB phase-1 records
  const size_t HBB_OFF  = TMP_OFF;                 // 25.6 MB bf16 h (table B), overlays tmp
  const size_t need = HBB_OFF + 25600000;          // ~65.0 MB

  if (ws_size >= need) {
    int* deg     = (int*)(ws + DEG_OFF);
    int* off     = (int*)(ws + OFF_OFF);
    int* bsum    = (int*)(ws + BSUM_OFF);
    int* boff    = (int*)(ws + BOFF_OFF);
    int* gcur    = (int*)(ws + GCUR_OFF);
    ushort* W1t  = (ushort*)(ws + WT1_OFF);
    ushort* W2t  = (ushort*)(ws + WT2_OFF);
    uint2* rec   = (uint2*)(ws + REC_OFF);
    ushort* hba  = (ushort*)(ws + HBA_OFF);
    uint2* tmp   = (uint2*)(ws + TMP_OFF);
    ushort* hbb  = (ushort*)(ws + HBB_OFF);

    node_init_kernel<<<2048, 256, 0, stream>>>(x, W_in, b_in, h, hba);

    // CSR build
    hipMemsetAsync(deg, 0, N_NODES * sizeof(int), stream);
    k_hist<<<(N_EDGES + 255) / 256, 256, 0, stream>>>(dsts, deg);
    k_chunk_sum<<<NCHUNK, 256, 0, stream>>>(deg, bsum);
    k_scan_bsum<<<1, 512, 0, stream>>>(bsum, boff);
    k_off<<<NCHUNK, 256, 0, stream>>>(deg, boff, off);
    k_gcur<<<1, 256, 0, stream>>>(off, gcur);
    k_wprep<<<(HIDDEN * HIDDEN + 255) / 256, 256, 0, stream>>>(W1, W2, W1t, W2t);
    k_bucket_scatter<<<(N_EDGES + P1_EDGES - 1) / P1_EDGES, 256, 0, stream>>>(
        srcs, dsts, ea2, gcur, tmp);
    k_bucket_sort<<<NBUCK, 256, 0, stream>>>(tmp, off, rec);

    const int cblocks = (N_NODES + 63) / 64;
    // conv1: read h/hba, write h + hbb
    conv_fused<<<cblocks, 256, 0, stream>>>(off, deg, rec, W_e, b_e, h,
                                            (const uint*)hba, W1t, W2t, b1, b2,
                                            h, hbb, 1);
    // conv2: read h/hbb, write h
    conv_fused<<<cblocks, 256, 0, stream>>>(off, deg, rec, W_e, b_e, h,
                                            (const uint*)hbb, W1t, W2t, b1, b2,
                                            h, nullptr, 0);
  } else {
    // Fallback: atomic scatter path
    float* agg = (float*)d_ws;
    const size_t agg_bytes = (size_t)N_NODES * HIDDEN * sizeof(float);

    node_init_kernel<<<2048, 256, 0, stream>>>(x, W_in, b_in, h, nullptr);

    hipMemsetAsync(agg, 0, agg_bytes, stream);
    edge_scatter_kernel<<<4096, 256, 0, stream>>>(ei, ea, W_e, b_e, h, agg);
    mlp_f32_kernel<true><<<N_NODES / 32, 256, 0, stream>>>(h, agg, W1, b1, W2, b2, h);

    hipMemsetAsync(agg, 0, agg_bytes, stream);
    edge_scatter_kernel<<<4096, 256, 0, stream>>>(ei, ea, W_e, b_e, h, agg);
    mlp_f32_kernel<false><<<N_NODES / 32, 256, 0, stream>>>(h, agg, W1, b1, W2, b2, h);
  }
}

// Round 5
// 465.019 us; speedup vs baseline: 3.6374x; 1.0114x over previous
//
#include <hip/hip_runtime.h>

#define N_NODES 100000
#define N_EDGES 1600000
#define NODE_DIM 24
#define HIDDEN 128
#define NCHUNK 391   // ceil(N_NODES/256)
#define BSHIFT 9     // 512 nodes per bucket
#define NBUCK 196    // ceil(100000/512)
#define P1_EDGES 2048

typedef __attribute__((ext_vector_type(8))) short bf16x8;
typedef __attribute__((ext_vector_type(4))) float f32x4;

__device__ __forceinline__ ushort f2bf(float f) {
  uint u = __builtin_bit_cast(uint, f);
  u += 0x7fffu + ((u >> 16) & 1u);  // RTNE
  return (ushort)(u >> 16);
}
__device__ __forceinline__ float bflo(uint v) { return __builtin_bit_cast(float, v << 16); }
__device__ __forceinline__ float bfhi(uint v) { return __builtin_bit_cast(float, v & 0xffff0000u); }

// ---------------------------------------------------------------------------
// K1: h0 = x @ W_in + b_in -> bf16 table (f32 only for fallback path)
// ---------------------------------------------------------------------------
__global__ __launch_bounds__(256) void node_init_kernel(
    const float* __restrict__ x, const float* __restrict__ W_in,
    const float* __restrict__ b_in, float* __restrict__ h,
    ushort* __restrict__ hb) {
  __shared__ float w_lds[NODE_DIM * HIDDEN];
  __shared__ float b_lds[HIDDEN];
  for (int i = threadIdx.x; i < NODE_DIM * HIDDEN; i += blockDim.x) w_lds[i] = W_in[i];
  if (threadIdx.x < HIDDEN) b_lds[threadIdx.x] = b_in[threadIdx.x];
  __syncthreads();
  const int j = threadIdx.x & 127;
  const int g = threadIdx.x >> 7;
  for (int n = blockIdx.x * 2 + g; n < N_NODES; n += gridDim.x * 2) {
    float acc = b_lds[j];
    const float* xr = x + (size_t)n * NODE_DIM;
#pragma unroll
    for (int d = 0; d < NODE_DIM; ++d) acc = fmaf(xr[d], w_lds[d * HIDDEN + j], acc);
    if (h) h[(size_t)n * HIDDEN + j] = acc;
    if (hb) hb[(size_t)n * HIDDEN + j] = f2bf(acc);
  }
}

// ---------------------------------------------------------------------------
// CSR degree/offsets
// ---------------------------------------------------------------------------
__global__ __launch_bounds__(256) void k_hist(const int* __restrict__ dsts,
                                              int* __restrict__ deg) {
  int e = blockIdx.x * 256 + threadIdx.x;
  if (e < N_EDGES) atomicAdd(&deg[dsts[e]], 1);
}

__global__ __launch_bounds__(256) void k_chunk_sum(const int* __restrict__ deg,
                                                   int* __restrict__ bsum) {
  __shared__ int s[256];
  int n = blockIdx.x * 256 + threadIdx.x;
  s[threadIdx.x] = (n < N_NODES) ? deg[n] : 0;
  __syncthreads();
  for (int d = 128; d > 0; d >>= 1) {
    if (threadIdx.x < d) s[threadIdx.x] += s[threadIdx.x + d];
    __syncthreads();
  }
  if (threadIdx.x == 0) bsum[blockIdx.x] = s[0];
}

__global__ __launch_bounds__(512) void k_scan_bsum(const int* __restrict__ bsum,
                                                   int* __restrict__ boff) {
  __shared__ int s[512];
  const int t = threadIdx.x;
  int v = (t < NCHUNK) ? bsum[t] : 0;
  s[t] = v;
  __syncthreads();
  for (int d = 1; d < 512; d <<= 1) {
    int x = (t >= d) ? s[t - d] : 0;
    __syncthreads();
    s[t] += x;
    __syncthreads();
  }
  if (t < NCHUNK) boff[t] = s[t] - v;  // exclusive
}

__global__ __launch_bounds__(256) void k_off(const int* __restrict__ deg,
                                             const int* __restrict__ boff,
                                             int* __restrict__ off) {
  __shared__ int s[256];
  const int t = threadIdx.x;
  int n = blockIdx.x * 256 + t;
  int v = (n < N_NODES) ? deg[n] : 0;
  s[t] = v;
  __syncthreads();
  for (int d = 1; d < 256; d <<= 1) {
    int x = (t >= d) ? s[t - d] : 0;
    __syncthreads();
    s[t] += x;
    __syncthreads();
  }
  if (n < N_NODES) off[n] = boff[blockIdx.x] + s[t] - v;
}

__global__ __launch_bounds__(256) void k_gcur(const int* __restrict__ off,
                                              int* __restrict__ gcur) {
  const int b = threadIdx.x;
  if (b < NBUCK) gcur[b] = off[b << BSHIFT];
}

// ---------------------------------------------------------------------------
// Phase 1: bucket scatter (grouped, coalesced writes)
// ---------------------------------------------------------------------------
__global__ __launch_bounds__(256) void k_bucket_scatter(
    const int* __restrict__ srcs, const int* __restrict__ dsts,
    const float2* __restrict__ ea2, int* __restrict__ gcur,
    uint2* __restrict__ tmp) {
  __shared__ int hist[256];
  __shared__ int sc[256];
  __shared__ int lofs[256];
  __shared__ int base[256];
  __shared__ int cur2[256];
  __shared__ uint2 stage[P1_EDGES];
  __shared__ uchar stage_b[P1_EDGES];
  const int t = threadIdx.x;
  const int e0 = blockIdx.x * P1_EDGES;

  hist[t] = 0;
  cur2[t] = 0;
  __syncthreads();

  uint rw0[8], rw1[8];
  int rb[8];
#pragma unroll
  for (int i = 0; i < 8; ++i) {
    const int e = e0 + t + i * 256;
    if (e < N_EDGES) {
      const int s = srcs[e];
      const int d = dsts[e];
      const float2 a = ea2[e];
      const int b = d >> BSHIFT;
      rb[i] = b;
      rw0[i] = (uint)s | ((uint)(d & 511) << 20);
      rw1[i] = (uint)f2bf(a.x) | ((uint)f2bf(a.y) << 16);
      atomicAdd(&hist[b], 1);
    } else {
      rb[i] = -1;
    }
  }
  __syncthreads();

  int v = hist[t];
  sc[t] = v;
  __syncthreads();
  for (int d = 1; d < 256; d <<= 1) {
    int x = (t >= d) ? sc[t - d] : 0;
    __syncthreads();
    sc[t] += x;
    __syncthreads();
  }
  lofs[t] = sc[t] - v;
  base[t] = (t < NBUCK && v > 0) ? atomicAdd(&gcur[t], v) : 0;
  __syncthreads();

#pragma unroll
  for (int i = 0; i < 8; ++i) {
    if (rb[i] >= 0) {
      const int l = atomicAdd(&cur2[rb[i]], 1);
      const int slot = lofs[rb[i]] + l;
      stage[slot] = make_uint2(rw0[i], rw1[i]);
      stage_b[slot] = (uchar)rb[i];
    }
  }
  __syncthreads();

  const int total = (N_EDGES - e0 < P1_EDGES) ? (N_EDGES - e0) : P1_EDGES;
  for (int s = t; s < total; s += 256) {
    const int b = stage_b[s];
    tmp[base[b] + (s - lofs[b])] = stage[s];
  }
}

// ---------------------------------------------------------------------------
// Phase 2: per-bucket counting sort into final CSR order
// ---------------------------------------------------------------------------
__global__ __launch_bounds__(256) void k_bucket_sort(
    const uint2* __restrict__ tmp, const int* __restrict__ off,
    uint2* __restrict__ rec) {
  __shared__ int lcur[512];
  const int b = blockIdx.x;
  const int nb0 = b << BSHIFT;
  for (int i = threadIdx.x; i < 512; i += 256) {
    const int n = nb0 + i;
    lcur[i] = (n < N_NODES) ? off[n] : 0;
  }
  __syncthreads();
  const int s0 = off[nb0];
  const int s1 = (nb0 + 512 >= N_NODES) ? N_EDGES : off[nb0 + 512];
  for (int s = s0 + threadIdx.x; s < s1; s += 256) {
    const uint2 r = tmp[s];
    const int dl = (r.x >> 20) & 511;
    const int p = atomicAdd(&lcur[dl], 1);
    rec[p] = make_uint2(r.x & 0xFFFFFu, r.y);
  }
}

// ---------------------------------------------------------------------------
// Weight prep: W1t/W2t[n][k] = bf16(W[k][n])
// ---------------------------------------------------------------------------
__global__ __launch_bounds__(256) void k_wprep(const float* __restrict__ W1,
                                               const float* __restrict__ W2,
                                               ushort* __restrict__ W1t,
                                               ushort* __restrict__ W2t) {
  int i = blockIdx.x * 256 + threadIdx.x;
  if (i < HIDDEN * HIDDEN) {
    int k = i >> 7, n = i & 127;
    W1t[n * HIDDEN + k] = f2bf(W1[k * HIDDEN + n]);
    W2t[n * HIDDEN + k] = f2bf(W2[k * HIDDEN + n]);
  }
}

// ---------------------------------------------------------------------------
// Fused conv. Single 17.4KB LDS buffer (z and t aliased) -> 8 blocks/CU.
// Self-term from bf16 table; outputs: optional f32, optional bf16 table.
// ---------------------------------------------------------------------------
__global__ __launch_bounds__(256) void conv_fused(
    const int* __restrict__ off, const int* __restrict__ deg,
    const uint2* __restrict__ rec, const float* __restrict__ W_e,
    const float* __restrict__ b_e, const uint* __restrict__ hb32,
    const ushort* __restrict__ W1t, const ushort* __restrict__ W2t,
    const float* __restrict__ bias1, const float* __restrict__ bias2,
    float* __restrict__ outf, ushort* __restrict__ outb, const int relu_out) {
  __shared__ short zs[64][136];
  const int tid = threadIdx.x;
  const int lane = tid & 63;
  const int wave = tid >> 6;
  const int n0 = blockIdx.x * 64;
  const int nrows = (N_NODES - n0 < 64) ? (N_NODES - n0) : 64;

  // ---- gather phase ----
  {
    const int j0 = lane * 2;
    const float we00 = W_e[j0], we01 = W_e[j0 + 1];
    const float we10 = W_e[HIDDEN + j0], we11 = W_e[HIDDEN + j0 + 1];
    const float eb0 = b_e[j0], eb1 = b_e[j0 + 1];
    for (int i = 0; i < 16; ++i) {
      const int n = n0 + wave * 16 + i;
      uint packed = 0;
      if (n < N_NODES) {
        const uint hv = hb32[(size_t)n * 64 + lane];
        float a0 = bflo(hv), a1 = bfhi(hv);
        const int o = off[n];
        const int dn = deg[n];
        int t2 = 0;
        for (; t2 + 4 <= dn; t2 += 4) {
          const uint2 r0 = rec[o + t2], r1 = rec[o + t2 + 1];
          const uint2 r2 = rec[o + t2 + 2], r3 = rec[o + t2 + 3];
          const uint v0 = hb32[(size_t)r0.x * 64 + lane];
          const uint v1 = hb32[(size_t)r1.x * 64 + lane];
          const uint v2 = hb32[(size_t)r2.x * 64 + lane];
          const uint v3 = hb32[(size_t)r3.x * 64 + lane];
          const float m00 = bflo(v0) + fmaf(bflo(r0.y), we00, fmaf(bfhi(r0.y), we10, eb0));
          const float m01 = bfhi(v0) + fmaf(bflo(r0.y), we01, fmaf(bfhi(r0.y), we11, eb1));
          const float m10 = bflo(v1) + fmaf(bflo(r1.y), we00, fmaf(bfhi(r1.y), we10, eb0));
          const float m11 = bfhi(v1) + fmaf(bflo(r1.y), we01, fmaf(bfhi(r1.y), we11, eb1));
          const float m20 = bflo(v2) + fmaf(bflo(r2.y), we00, fmaf(bfhi(r2.y), we10, eb0));
          const float m21 = bfhi(v2) + fmaf(bflo(r2.y), we01, fmaf(bfhi(r2.y), we11, eb1));
          const float m30 = bflo(v3) + fmaf(bflo(r3.y), we00, fmaf(bfhi(r3.y), we10, eb0));
          const float m31 = bfhi(v3) + fmaf(bflo(r3.y), we01, fmaf(bfhi(r3.y), we11, eb1));
          a0 += (fmaxf(m00, 0.f) + fmaxf(m10, 0.f)) + (fmaxf(m20, 0.f) + fmaxf(m30, 0.f));
          a1 += (fmaxf(m01, 0.f) + fmaxf(m11, 0.f)) + (fmaxf(m21, 0.f) + fmaxf(m31, 0.f));
        }
        for (; t2 < dn; ++t2) {
          const uint2 r0 = rec[o + t2];
          const uint v0 = hb32[(size_t)r0.x * 64 + lane];
          const float m00 = bflo(v0) + fmaf(bflo(r0.y), we00, fmaf(bfhi(r0.y), we10, eb0));
          const float m01 = bfhi(v0) + fmaf(bflo(r0.y), we01, fmaf(bfhi(r0.y), we11, eb1));
          a0 += fmaxf(m00, 0.f);
          a1 += fmaxf(m01, 0.f);
        }
        packed = (uint)f2bf(a0) | ((uint)f2bf(a1) << 16);
      }
      *(uint*)&zs[wave * 16 + i][lane * 2] = packed;
    }
  }
  __syncthreads();

  // ---- MLP phase (MFMA), z/t aliased in zs ----
  const int l15 = lane & 15;
  const int kq = lane >> 4;
  const int colbase = wave * 32;
  const int c0 = colbase + l15, c1 = colbase + 16 + l15;

  f32x4 acc[4][2];
  {
    const float bb0 = bias1[c0], bb1 = bias1[c1];
#pragma unroll
    for (int mt = 0; mt < 4; ++mt) {
      acc[mt][0] = (f32x4){bb0, bb0, bb0, bb0};
      acc[mt][1] = (f32x4){bb1, bb1, bb1, bb1};
    }
  }
#pragma unroll
  for (int kt = 0; kt < 4; ++kt) {
    const int kk = kt * 32 + kq * 8;
    const bf16x8 bf0 = *(const bf16x8*)&W1t[(size_t)c0 * HIDDEN + kk];
    const bf16x8 bf1 = *(const bf16x8*)&W1t[(size_t)c1 * HIDDEN + kk];
#pragma unroll
    for (int mt = 0; mt < 4; ++mt) {
      const bf16x8 a = *(const bf16x8*)&zs[mt * 16 + l15][kk];
      acc[mt][0] = __builtin_amdgcn_mfma_f32_16x16x32_bf16(a, bf0, acc[mt][0], 0, 0, 0);
      acc[mt][1] = __builtin_amdgcn_mfma_f32_16x16x32_bf16(a, bf1, acc[mt][1], 0, 0, 0);
    }
  }
  __syncthreads();  // all layer-1 reads of zs complete
#pragma unroll
  for (int mt = 0; mt < 4; ++mt)
#pragma unroll
    for (int nt = 0; nt < 2; ++nt)
#pragma unroll
      for (int r = 0; r < 4; ++r) {
        const int row = mt * 16 + kq * 4 + r;
        const int col = colbase + nt * 16 + l15;
        float v = acc[mt][nt][r];
        zs[row][col] = (short)f2bf(v > 0.f ? v : 0.f);
      }
  __syncthreads();

  {
    const float bb0 = bias2[c0], bb1 = bias2[c1];
#pragma unroll
    for (int mt = 0; mt < 4; ++mt) {
      acc[mt][0] = (f32x4){bb0, bb0, bb0, bb0};
      acc[mt][1] = (f32x4){bb1, bb1, bb1, bb1};
    }
  }
#pragma unroll
  for (int kt = 0; kt < 4; ++kt) {
    const int kk = kt * 32 + kq * 8;
    const bf16x8 bf0 = *(const bf16x8*)&W2t[(size_t)c0 * HIDDEN + kk];
    const bf16x8 bf1 = *(const bf16x8*)&W2t[(size_t)c1 * HIDDEN + kk];
#pragma unroll
    for (int mt = 0; mt < 4; ++mt) {
      const bf16x8 a = *(const bf16x8*)&zs[mt * 16 + l15][kk];
      acc[mt][0] = __builtin_amdgcn_mfma_f32_16x16x32_bf16(a, bf0, acc[mt][0], 0, 0, 0);
      acc[mt][1] = __builtin_amdgcn_mfma_f32_16x16x32_bf16(a, bf1, acc[mt][1], 0, 0, 0);
    }
  }
#pragma unroll
  for (int mt = 0; mt < 4; ++mt)
#pragma unroll
    for (int nt = 0; nt < 2; ++nt)
#pragma unroll
      for (int r = 0; r < 4; ++r) {
        const int row = mt * 16 + kq * 4 + r;
        if (row < nrows) {
          const int col = colbase + nt * 16 + l15;
          float v = acc[mt][nt][r];
          if (relu_out) v = v > 0.f ? v : 0.f;
          if (outf) outf[(size_t)(n0 + row) * HIDDEN + col] = v;
          if (outb) outb[(size_t)(n0 + row) * HIDDEN + col] = f2bf(v);
        }
      }
}

// ---------------------------------------------------------------------------
// Fallback path (atomic scatter + f32 MLP), used only if ws too small
// ---------------------------------------------------------------------------
__global__ __launch_bounds__(256) void edge_scatter_kernel(
    const int* __restrict__ ei, const float* __restrict__ ea,
    const float* __restrict__ W_e, const float* __restrict__ b_e,
    const float* __restrict__ h, float* __restrict__ agg) {
  const int j = threadIdx.x & 127;
  const int g = threadIdx.x >> 7;
  const float we0 = W_e[j];
  const float we1 = W_e[HIDDEN + j];
  const float be = b_e[j];
  const int* __restrict__ srcs = ei;
  const int* __restrict__ dsts = ei + N_EDGES;
  const float2* __restrict__ ea2 = (const float2*)ea;
  for (int e = blockIdx.x * 2 + g; e < N_EDGES; e += gridDim.x * 2) {
    const int s = srcs[e];
    const int d = dsts[e];
    const float2 a = ea2[e];
    float m = h[(size_t)s * HIDDEN + j] + fmaf(a.x, we0, fmaf(a.y, we1, be));
    m = m > 0.f ? m : 0.f;
    unsafeAtomicAdd(&agg[(size_t)d * HIDDEN + j], m);
  }
}

template <bool RELU_OUT>
__global__ __launch_bounds__(256) void mlp_f32_kernel(
    const float* __restrict__ zbuf, const float* __restrict__ agg,
    const float* __restrict__ W1, const float* __restrict__ b1,
    const float* __restrict__ W2, const float* __restrict__ b2,
    float* __restrict__ out) {
  const int NB = 32;
  const int NT = 16;
  __shared__ float zs[NB][HIDDEN];
  __shared__ float ts[NB][HIDDEN];
  const int j = threadIdx.x & 127;
  const int g = threadIdx.x >> 7;
  const int n0 = blockIdx.x * NB;

#pragma unroll
  for (int n = 0; n < NT; ++n) {
    const int nn = g * NT + n;
    zs[nn][j] = zbuf[(size_t)(n0 + nn) * HIDDEN + j] + agg[(size_t)(n0 + nn) * HIDDEN + j];
  }
  __syncthreads();

  float acc[NT];
  const float b1j = b1[j];
#pragma unroll
  for (int n = 0; n < NT; ++n) acc[n] = b1j;
  for (int k = 0; k < HIDDEN; k += 4) {
    const float w0 = W1[(k + 0) * HIDDEN + j];
    const float w1 = W1[(k + 1) * HIDDEN + j];
    const float w2 = W1[(k + 2) * HIDDEN + j];
    const float w3 = W1[(k + 3) * HIDDEN + j];
#pragma unroll
    for (int n = 0; n < NT; ++n) {
      const float4 z = *reinterpret_cast<const float4*>(&zs[g * NT + n][k]);
      acc[n] = fmaf(z.x, w0, acc[n]);
      acc[n] = fmaf(z.y, w1, acc[n]);
      acc[n] = fmaf(z.z, w2, acc[n]);
      acc[n] = fmaf(z.w, w3, acc[n]);
    }
  }
#pragma unroll
  for (int n = 0; n < NT; ++n) ts[g * NT + n][j] = acc[n] > 0.f ? acc[n] : 0.f;
  __syncthreads();

  const float b2j = b2[j];
#pragma unroll
  for (int n = 0; n < NT; ++n) acc[n] = b2j;
  for (int k = 0; k < HIDDEN; k += 4) {
    const float w0 = W2[(k + 0) * HIDDEN + j];
    const float w1 = W2[(k + 1) * HIDDEN + j];
    const float w2 = W2[(k + 2) * HIDDEN + j];
    const float w3 = W2[(k + 3) * HIDDEN + j];
#pragma unroll
    for (int n = 0; n < NT; ++n) {
      const float4 z = *reinterpret_cast<const float4*>(&ts[g * NT + n][k]);
      acc[n] = fmaf(z.x, w0, acc[n]);
      acc[n] = fmaf(z.y, w1, acc[n]);
      acc[n] = fmaf(z.z, w2, acc[n]);
      acc[n] = fmaf(z.w, w3, acc[n]);
    }
  }
#pragma unroll
  for (int n = 0; n < NT; ++n) {
    float v = acc[n];
    if (RELU_OUT) v = v > 0.f ? v : 0.f;
    out[(size_t)(n0 + g * NT + n) * HIDDEN + j] = v;
  }
}

extern "C" void kernel_launch(void* const* d_in, const int* in_sizes, int n_in,
                              void* d_out, int out_size, void* d_ws, size_t ws_size,
                              hipStream_t stream) {
  const float* x    = (const float*)d_in[0];
  const int*   ei   = (const int*)d_in[1];
  const float* ea   = (const float*)d_in[2];
  const float* W_in = (const float*)d_in[3];
  const float* b_in = (const float*)d_in[4];
  const float* W_e  = (const float*)d_in[5];
  const float* b_e  = (const float*)d_in[6];
  const float* W1   = (const float*)d_in[7];
  const float* b1   = (const float*)d_in[8];
  const float* W2   = (const float*)d_in[9];
  const float* b2   = (const float*)d_in[10];

  const int* srcs = ei;
  const int* dsts = ei + N_EDGES;
  const float2* ea2 = (const float2*)ea;

  float* h = (float*)d_out;  // final f32 output
  char* ws = (char*)d_ws;

  // ws layout. tmp (phase-1 output) is overlaid with hb_b (dead after sort).
  const size_t DEG_OFF  = 0;                       // 400000
  const size_t OFF_OFF  = 400000;                  // 400000
  const size_t BSUM_OFF = 800000;                  // ~1.6KB
  const size_t BOFF_OFF = 804096;                  // ~1.6KB
  const size_t GCUR_OFF = 808192;                  // 784 B
  const size_t WT1_OFF  = 812288;                  // 32768
  const size_t WT2_OFF  = 845056;                  // 32768
  const size_t REC_OFF  = 1048576;                 // 12.8 MB final CSR records
  const size_t HBA_OFF  = REC_OFF + 12800000;      // 25.6 MB bf16 h (table A)
  const size_t TMP_OFF  = HBA_OFF + 25600000;      // 12.8 MB phase-1 records
  const size_t HBB_OFF  = TMP_OFF;                 // 25.6 MB bf16 h (table B)
  const size_t need = HBB_OFF + 25600000;          // ~65.0 MB

  if (ws_size >= need) {
    int* deg     = (int*)(ws + DEG_OFF);
    int* off     = (int*)(ws + OFF_OFF);
    int* bsum    = (int*)(ws + BSUM_OFF);
    int* boff    = (int*)(ws + BOFF_OFF);
    int* gcur    = (int*)(ws + GCUR_OFF);
    ushort* W1t  = (ushort*)(ws + WT1_OFF);
    ushort* W2t  = (ushort*)(ws + WT2_OFF);
    uint2* rec   = (uint2*)(ws + REC_OFF);
    ushort* hba  = (ushort*)(ws + HBA_OFF);
    uint2* tmp   = (uint2*)(ws + TMP_OFF);
    ushort* hbb  = (ushort*)(ws + HBB_OFF);

    // h0 -> bf16 table only (no f32 write needed on the fast path)
    node_init_kernel<<<2048, 256, 0, stream>>>(x, W_in, b_in, nullptr, hba);

    // CSR build
    hipMemsetAsync(deg, 0, N_NODES * sizeof(int), stream);
    k_hist<<<(N_EDGES + 255) / 256, 256, 0, stream>>>(dsts, deg);
    k_chunk_sum<<<NCHUNK, 256, 0, stream>>>(deg, bsum);
    k_scan_bsum<<<1, 512, 0, stream>>>(bsum, boff);
    k_off<<<NCHUNK, 256, 0, stream>>>(deg, boff, off);
    k_gcur<<<1, 256, 0, stream>>>(off, gcur);
    k_wprep<<<(HIDDEN * HIDDEN + 255) / 256, 256, 0, stream>>>(W1, W2, W1t, W2t);
    k_bucket_scatter<<<(N_EDGES + P1_EDGES - 1) / P1_EDGES, 256, 0, stream>>>(
        srcs, dsts, ea2, gcur, tmp);
    k_bucket_sort<<<NBUCK, 256, 0, stream>>>(tmp, off, rec);

    const int cblocks = (N_NODES + 63) / 64;
    // conv1: read hba -> write hbb (bf16 only)
    conv_fused<<<cblocks, 256, 0, stream>>>(off, deg, rec, W_e, b_e,
                                            (const uint*)hba, W1t, W2t, b1, b2,
                                            nullptr, hbb, 1);
    // conv2: read hbb -> write final f32 out
    conv_fused<<<cblocks, 256, 0, stream>>>(off, deg, rec, W_e, b_e,
                                            (const uint*)hbb, W1t, W2t, b1, b2,
                                            h, nullptr, 0);
  } else {
    // Fallback: atomic scatter path
    float* agg = (float*)d_ws;
    const size_t agg_bytes = (size_t)N_NODES * HIDDEN * sizeof(float);

    node_init_kernel<<<2048, 256, 0, stream>>>(x, W_in, b_in, h, nullptr);

    hipMemsetAsync(agg, 0, agg_bytes, stream);
    edge_scatter_kernel<<<4096, 256, 0, stream>>>(ei, ea, W_e, b_e, h, agg);
    mlp_f32_kernel<true><<<N_NODES / 32, 256, 0, stream>>>(h, agg, W1, b1, W2, b2, h);

    hipMemsetAsync(agg, 0, agg_bytes, stream);
    edge_scatter_kernel<<<4096, 256, 0, stream>>>(ei, ea, W_e, b_e, h, agg);
    mlp_f32_kernel<false><<<N_NODES / 32, 256, 0, stream>>>(h, agg, W1, b1, W2, b2, h);
  }
}